// Round 6
// baseline (226.710 us; speedup 1.0000x reference)
//
#include <hip/hip_runtime.h>
#include <hip/hip_bf16.h>

// Problem constants: B=2, C=128, T=512, F=512, H=8, d=64
#define CC 128
#define TT 512
#define FF 512
#define CS (TT * FF)

typedef __attribute__((ext_vector_type(8))) short short8;
typedef __attribute__((ext_vector_type(4))) float f32x4;
typedef __attribute__((ext_vector_type(4))) unsigned short u16x4;

__device__ __forceinline__ unsigned short f2b(float f) {
    union { float f; unsigned u; } a; a.f = f;
    unsigned r = a.u + 0x7fffu + ((a.u >> 16) & 1u);   // RNE to bf16
    return (unsigned short)(r >> 16);
}

// ---------------------------------------------------------------------------
// Kernel A: xm[b,c,f] = mean_t x[b,c,t,f].  grid=256 (b*C+c), block=1024.
// (R3 version — measured ~62 us.)
// ---------------------------------------------------------------------------
__global__ __launch_bounds__(1024) void mean_kernel(const float* __restrict__ x,
                                                    float* __restrict__ xm) {
    int bc = blockIdx.x;
    int q4  = threadIdx.x & 127;
    int par = threadIdx.x >> 7;
    const float4* xp = (const float4*)(x + (size_t)bc * (TT * FF));
    float4 s0 = make_float4(0.f,0.f,0.f,0.f), s1 = make_float4(0.f,0.f,0.f,0.f);
    float4 s2 = make_float4(0.f,0.f,0.f,0.f), s3 = make_float4(0.f,0.f,0.f,0.f);
    #pragma unroll 4
    for (int k = 0; k < 64; k += 4) {
        float4 a = xp[(par + 8 * k) * 128 + q4];
        float4 b = xp[(par + 8 * (k + 1)) * 128 + q4];
        float4 c = xp[(par + 8 * (k + 2)) * 128 + q4];
        float4 d = xp[(par + 8 * (k + 3)) * 128 + q4];
        s0.x += a.x; s0.y += a.y; s0.z += a.z; s0.w += a.w;
        s1.x += b.x; s1.y += b.y; s1.z += b.z; s1.w += b.w;
        s2.x += c.x; s2.y += c.y; s2.z += c.z; s2.w += c.w;
        s3.x += d.x; s3.y += d.y; s3.z += d.z; s3.w += d.w;
    }
    s0.x += s1.x + s2.x + s3.x; s0.y += s1.y + s2.y + s3.y;
    s0.z += s1.z + s2.z + s3.z; s0.w += s1.w + s2.w + s3.w;
    __shared__ float4 part[1024];
    part[threadIdx.x] = s0;
    __syncthreads();
    if (par == 0) {
        const float inv = 1.0f / (float)TT;
        float4 acc = make_float4(0.f,0.f,0.f,0.f);
        #pragma unroll
        for (int j = 0; j < 8; ++j) {
            float4 v = part[q4 + 128 * j];
            acc.x += v.x; acc.y += v.y; acc.z += v.z; acc.w += v.w;
        }
        acc.x *= inv; acc.y *= inv; acc.z *= inv; acc.w *= inv;
        ((float4*)xm)[bc * 128 + q4] = acc;
    }
}

// ---------------------------------------------------------------------------
// Kernel B1: q = xm @ Wq^T + bq ; k = xm @ Wk^T
// ---------------------------------------------------------------------------
__global__ void qk_kernel(const float* __restrict__ xm, const float* __restrict__ Wq,
                          const float* __restrict__ bq, const float* __restrict__ Wk,
                          float* __restrict__ qo, float* __restrict__ ko) {
    __shared__ float xs[32][65];
    __shared__ float wqs[32][65];
    __shared__ float wks[32][65];
    int ft = blockIdx.x, rt = blockIdx.y;
    int t = threadIdx.x;
    int tx = t & 15, ty = t >> 4;
    float qa[2][2] = {{0.f,0.f},{0.f,0.f}}, ka[2][2] = {{0.f,0.f},{0.f,0.f}};
    for (int kc = 0; kc < 512; kc += 64) {
        __syncthreads();
        for (int i = t; i < 2048; i += 256) {
            int r = i >> 6, cc2 = i & 63;
            xs[r][cc2]  = xm[(rt * 32 + r) * 512 + kc + cc2];
            wqs[r][cc2] = Wq[(ft * 32 + r) * 512 + kc + cc2];
            wks[r][cc2] = Wk[(ft * 32 + r) * 512 + kc + cc2];
        }
        __syncthreads();
        #pragma unroll 8
        for (int kk = 0; kk < 64; ++kk) {
            float x0 = xs[ty*2][kk],  x1 = xs[ty*2+1][kk];
            float a0 = wqs[tx*2][kk], a1 = wqs[tx*2+1][kk];
            float b0 = wks[tx*2][kk], b1 = wks[tx*2+1][kk];
            qa[0][0] += x0*a0; qa[0][1] += x0*a1;
            qa[1][0] += x1*a0; qa[1][1] += x1*a1;
            ka[0][0] += x0*b0; ka[0][1] += x0*b1;
            ka[1][0] += x1*b0; ka[1][1] += x1*b1;
        }
    }
    #pragma unroll
    for (int i = 0; i < 2; ++i) {
        int r = rt * 32 + ty * 2 + i;
        #pragma unroll
        for (int j = 0; j < 2; ++j) {
            int f = ft * 32 + tx * 2 + j;
            qo[r * 512 + f] = qa[i][j] + bq[f];
            ko[r * 512 + f] = ka[i][j];
        }
    }
}

// ---------------------------------------------------------------------------
// Kernel B2: logits + softmax -> w[bh][c][c'].
// ---------------------------------------------------------------------------
__global__ void attn_w_kernel(const float* __restrict__ q, const float* __restrict__ k,
                              float* __restrict__ w) {
    int idx = blockIdx.x;
    int bh = idx >> 7, c = idx & 127;
    int b = bh >> 3, h = bh & 7;
    int f0 = h * 64;
    __shared__ float qv[64];
    __shared__ float wmax[2];
    __shared__ float wsum[2];
    int t = threadIdx.x;     // = c'
    if (t < 64) qv[t] = q[((b * CC + c) * FF) + f0 + t];
    __syncthreads();
    const float* kp = k + ((size_t)(b * CC + t) * FF) + f0;
    float acc = 0.f;
    #pragma unroll
    for (int j = 0; j < 64; j += 4) {
        float4 kv = *(const float4*)(kp + j);
        acc += qv[j] * kv.x + qv[j+1] * kv.y + qv[j+2] * kv.z + qv[j+3] * kv.w;
    }
    float logit = acc * 0.125f;   // d^{-1/2}, d = 64
    float m = logit;
    #pragma unroll
    for (int o = 32; o >= 1; o >>= 1) m = fmaxf(m, __shfl_xor(m, o));
    if ((t & 63) == 0) wmax[t >> 6] = m;
    __syncthreads();
    m = fmaxf(wmax[0], wmax[1]);
    float e = expf(logit - m);
    float s = e;
    #pragma unroll
    for (int o = 32; o >= 1; o >>= 1) s += __shfl_xor(s, o);
    if ((t & 63) == 0) wsum[t >> 6] = s;
    __syncthreads();
    s = wsum[0] + wsum[1];
    w[((size_t)bh * 128 + c) * 128 + t] = e / s;
}

// ---------------------------------------------------------------------------
// Kernel C (wv4): out[b,c,col] = sum_c' W[bh][c][c'] * x[b,c',col]
// Block = (bh, t-group of 8). Per t-tile: 64 cols x 128 c' (32 KB).
//  - x loaded as float4 (1 KB / wave-instr, 256 B contiguous per c'-row),
//    converted to bf16, 4x4-transposed in-register, ds_write_b64 into
//    Xt[col][c'] (XOR-swizzled) -> conflict-free b128 fragment reads.
//  - Register->LDS DOUBLE BUFFER: tile t+1 global loads issued before
//    compute of tile t, so 32 KB/block stays in flight continuously.
//  - MFMA: A = x-frag (rows = output cols), B = W-frag; b128 stores.
// grid = 1024 (16 bh x 64 tg), block = 256 (4 waves x 16 cols each).
// ---------------------------------------------------------------------------
__global__ __launch_bounds__(256, 2) void wv4_kernel(const float* __restrict__ x,
                                                     const float* __restrict__ wmat,
                                                     float* __restrict__ out) {
    int bid = blockIdx.x;
    int bh = bid >> 6;          // consecutive blocks share bh -> W L2-hot
    int tg = bid & 63;
    int b = bh >> 3, h = bh & 7;

    __shared__ unsigned short Wl[128 * 128];      // 32 KB swizzled bf16
    __shared__ unsigned short Xt[2][64 * 128];    // 2 x 16 KB [col][c'] swizzled

    int tid = threadIdx.x;
    const float* xb = x + (size_t)b * CC * CS + (h << 6);
    float* ob = out + (size_t)b * CC * CS + (h << 6);

    // staging geometry: thread -> (c' group of 4, col group of 4), 2 groups
    int colg = tid & 15;                 // cols colg*4 .. +3
    int cg0  = tid >> 4;                 // c' groups cg0 and cg0+16

    // -------- prologue: issue tile-0 x loads FIRST (fly during W staging) ----
    f32x4 xg[2][4];
    {
        int t0 = tg * 8;
        #pragma unroll
        for (int s = 0; s < 2; ++s) {
            int cp4 = (cg0 + s * 16) * 4;
            #pragma unroll
            for (int jj = 0; jj < 4; ++jj)
                xg[s][jj] = *(const f32x4*)(xb + (size_t)(cp4 + jj) * CS
                                               + (size_t)t0 * FF + colg * 4);
        }
    }

    // -------- stage W: row c, byte = c*256 + ((2e) ^ ((c&7)<<4)) -------------
    {
        int c = tid & 127, half = tid >> 7;
        const float* wp = wmat + ((size_t)bh * 128 + c) * 128 + half * 64;
        unsigned swz = (unsigned)((c & 7) << 4);
        char* base = (char*)Wl + c * 256;
        #pragma unroll
        for (int j = 0; j < 8; ++j) {
            f32x4 v0 = *(const f32x4*)(wp + j * 8);
            f32x4 v1 = *(const f32x4*)(wp + j * 8 + 4);
            short8 pk;
            pk[0] = (short)f2b(v0[0]); pk[1] = (short)f2b(v0[1]);
            pk[2] = (short)f2b(v0[2]); pk[3] = (short)f2b(v0[3]);
            pk[4] = (short)f2b(v1[0]); pk[5] = (short)f2b(v1[1]);
            pk[6] = (short)f2b(v1[2]); pk[7] = (short)f2b(v1[3]);
            *(short8*)(base + (((unsigned)(half * 128 + j * 16)) ^ swz)) = pk;
        }
    }

    int ln  = tid & 63;
    int wq  = tid >> 6;
    int l15 = ln & 15;
    int kg  = ln >> 4;
    unsigned xswz = (unsigned)((l15 & 7) << 4);

    for (int ti = 0; ti < 8; ++ti) {
        int t = tg * 8 + ti;
        char* xbuf = (char*)Xt[ti & 1];

        // convert + transposed LDS write of tile ti (waits on its loads)
        #pragma unroll
        for (int s = 0; s < 2; ++s) {
            int cp4 = (cg0 + s * 16) * 4;
            #pragma unroll
            for (int j = 0; j < 4; ++j) {
                int col = colg * 4 + j;
                u16x4 p = { f2b(xg[s][0][j]), f2b(xg[s][1][j]),
                            f2b(xg[s][2][j]), f2b(xg[s][3][j]) };
                *(u16x4*)(xbuf + (((unsigned)(col * 256 + cp4 * 2))
                                  ^ ((unsigned)((col & 7) << 4)))) = p;
            }
        }
        __syncthreads();

        // issue next tile's loads now; they fly under the compute below
        if (ti < 7) {
            int tn = t + 1;
            #pragma unroll
            for (int s = 0; s < 2; ++s) {
                int cp4 = (cg0 + s * 16) * 4;
                #pragma unroll
                for (int jj = 0; jj < 4; ++jj)
                    xg[s][jj] = *(const f32x4*)(xb + (size_t)(cp4 + jj) * CS
                                                   + (size_t)tn * FF + colg * 4);
            }
        }

        // compute: wave wq owns cols [wq*16, wq*16+16)
        f32x4 acc[8];
        #pragma unroll
        for (int ct = 0; ct < 8; ++ct) acc[ct] = (f32x4){0.f, 0.f, 0.f, 0.f};

        int coll = wq * 16 + l15;
        const char* xrow = xbuf + coll * 256;
        #pragma unroll
        for (int ks = 0; ks < 4; ++ks) {
            short8 af = *(const short8*)(xrow +
                            (((unsigned)(ks * 64 + kg * 16)) ^ xswz));
            #pragma unroll
            for (int ct = 0; ct < 8; ++ct) {
                int r = ct * 16 + l15;
                const char* bp = (const char*)Wl + r * 256;
                short8 wf = *(const short8*)(bp +
                                (((unsigned)(ks * 64 + kg * 16))
                                 ^ ((unsigned)((r & 7) << 4))));
                acc[ct] = __builtin_amdgcn_mfma_f32_16x16x32_bf16(af, wf, acc[ct], 0, 0, 0);
            }
        }

        // stores: lane holds out[c = ct*16+l15][f = col0 + wq*16 + kg*4 .. +3]
        float* o0 = ob + (size_t)t * FF + wq * 16 + kg * 4;
        #pragma unroll
        for (int ct = 0; ct < 8; ++ct)
            *(f32x4*)(o0 + (size_t)(ct * 16 + l15) * CS) = acc[ct];

        __syncthreads();   // protect Xt[(ti+1)&1] writes vs this tile's readers
    }
}

// ---------------------------------------------------------------------------
extern "C" void kernel_launch(void* const* d_in, const int* in_sizes, int n_in,
                              void* d_out, int out_size, void* d_ws, size_t ws_size,
                              hipStream_t stream) {
    (void)in_sizes; (void)n_in; (void)out_size; (void)ws_size;
    const float* x  = (const float*)d_in[0];
    const float* Wq = (const float*)d_in[1];
    const float* bq = (const float*)d_in[2];
    const float* Wk = (const float*)d_in[3];
    float* out = (float*)d_out;

    // workspace layout (floats): xm[131072] q[131072] k[131072] w[262144]
    float* ws = (float*)d_ws;
    float* xm = ws;
    float* q  = ws + 131072;
    float* k  = ws + 262144;
    float* w  = ws + 393216;

    hipLaunchKernelGGL(mean_kernel,   dim3(256),   dim3(1024), 0, stream, x, xm);
    hipLaunchKernelGGL(qk_kernel,     dim3(16, 8), dim3(256),  0, stream, xm, Wq, bq, Wk, q, k);
    hipLaunchKernelGGL(attn_w_kernel, dim3(2048),  dim3(128),  0, stream, q, k, w);
    hipLaunchKernelGGL(wv4_kernel,    dim3(1024),  dim3(256),  0, stream, x, w, out);
}